// Round 11
// baseline (283.268 us; speedup 1.0000x reference)
//
#include <hip/hip_runtime.h>
#include <hip/hip_bf16.h>

#define N_NODES 50000
#define N_EDGES 800000
#define HDIM 128
#define NGRAPH 512
#define NCLS 10
#define BN_EPS 1e-5f
#define MAXDEG 64   // in-deg ~ Poisson(16) over 50k bins; P(any>=64) ~ 1e-14

typedef unsigned int  uint32;
typedef unsigned short ushort16;

// bf16x2 (packed in a uint) -> float2
__device__ inline float2 bf2f(uint32 u) {
    return make_float2(__uint_as_float(u << 16), __uint_as_float(u & 0xffff0000u));
}
// fp32 -> bf16 bits, round-to-nearest-even
__device__ inline ushort16 f2bf(float f) {
    uint32 u = __float_as_uint(f);
    u += 0x7fffu + ((u >> 16) & 1u);
    return (ushort16)(u >> 16);
}
__device__ inline uint32 packbf2(float lo, float hi) {
    return (uint32)f2bf(lo) | ((uint32)f2bf(hi) << 16);
}
// bf16 round-trip in fp32 (keeps phase-2 inputs bit-identical to r10's bufB)
__device__ inline float bfround(float f) {
    return __uint_as_float((uint32)f2bf(f) << 16);
}

// NOTE (r6-r10 bisect): r10's numeric path = 4*2^-12 absmax (safe); the
// r6-restructured gather cluster = 11*2^-12 (fails post-timing). All gather /
// GEMM / pool inner numerics below are VERBATIM r10; fusions only move data
// through LDS with explicit bf16 round-trips so the bit-path is preserved.

#define GEMM1_BLOCKS 1563                  // ceil(50000/32)
#define FRONT_GRID (3 * GEMM1_BLOCKS)      // rem0: gemm1, rem1/2: bucket
#define AB_BLOCKS 1563                     // 32 nodes per block

// ---------------------------------------------------------------------------
// Fused front: rem!=0 blocks run bucket_edges (atomic-bound, VALU-idle),
// rem==0 blocks run gemm1 fp32 (VALU-bound). Bodies verbatim r5/r10.
// ---------------------------------------------------------------------------
__global__ __launch_bounds__(256) void front(const float* __restrict__ x,
                                             const float* __restrict__ W1,
                                             ushort16* __restrict__ bufA,
                                             const int* __restrict__ src,
                                             const int* __restrict__ dst,
                                             int* __restrict__ deg,
                                             int* __restrict__ epad)
{
    __shared__ float xs[32][36];
    __shared__ float ws[32][128];
    const int tid = threadIdx.x;
    const int grp = blockIdx.x / 3, rem = blockIdx.x % 3;

    if (rem != 0) {
        int e = (grp * 2 + (rem - 1)) * 256 + tid;
        if (e < N_EDGES) {
            int d   = dst[e];
            int pos = atomicAdd(&deg[d], 1);
            epad[(size_t)d * MAXDEG + pos] = src[e];
        }
        return;
    }

    const int row0 = grp * 32;
    const int tx   = tid & 31;
    const int ty   = tid >> 5;

    float acc[4][4];
    #pragma unroll
    for (int i = 0; i < 4; ++i)
        #pragma unroll
        for (int j = 0; j < 4; ++j) acc[i][j] = 0.f;

    const int lr = tid >> 3;
    const int lk = (tid & 7) << 2;
    const int wr = tid >> 5;
    const int wc = (tid & 31) << 2;

    for (int k0 = 0; k0 < 128; k0 += 32) {
        float4 xv = make_float4(0.f, 0.f, 0.f, 0.f);
        int grow = row0 + lr;
        if (grow < N_NODES) xv = *(const float4*)(x + (size_t)grow * HDIM + k0 + lk);
        xs[lr][lk] = xv.x; xs[lr][lk + 1] = xv.y; xs[lr][lk + 2] = xv.z; xs[lr][lk + 3] = xv.w;
        #pragma unroll
        for (int i = 0; i < 4; ++i) {
            int kk = wr + i * 8;
            *(float4*)&ws[kk][wc] = *(const float4*)(W1 + (size_t)(k0 + kk) * HDIM + wc);
        }
        __syncthreads();
        #pragma unroll
        for (int kk = 0; kk < 32; kk += 4) {
            float4 wv[4];
            #pragma unroll
            for (int j = 0; j < 4; ++j) wv[j] = *(const float4*)&ws[kk + j][tx << 2];
            #pragma unroll
            for (int i = 0; i < 4; ++i) {
                float4 xr = *(const float4*)&xs[ty * 4 + i][kk];
                acc[i][0] += xr.x * wv[0].x; acc[i][1] += xr.x * wv[0].y;
                acc[i][2] += xr.x * wv[0].z; acc[i][3] += xr.x * wv[0].w;
                acc[i][0] += xr.y * wv[1].x; acc[i][1] += xr.y * wv[1].y;
                acc[i][2] += xr.y * wv[1].z; acc[i][3] += xr.y * wv[1].w;
                acc[i][0] += xr.z * wv[2].x; acc[i][1] += xr.z * wv[2].y;
                acc[i][2] += xr.z * wv[2].z; acc[i][3] += xr.z * wv[2].w;
                acc[i][0] += xr.w * wv[3].x; acc[i][1] += xr.w * wv[3].y;
                acc[i][2] += xr.w * wv[3].z; acc[i][3] += xr.w * wv[3].w;
            }
        }
        __syncthreads();
    }
    #pragma unroll
    for (int i = 0; i < 4; ++i) {
        int grow = row0 + ty * 4 + i;
        if (grow < N_NODES) {
            uint2 o;
            o.x = packbf2(acc[i][0], acc[i][1]);
            o.y = packbf2(acc[i][2], acc[i][3]);
            *(uint2*)(bufA + (size_t)grow * HDIM + (tx << 2)) = o;
        }
    }
}

// dis[i] = rsqrt(deg[i] + 1)   (+1 = self loop)  -- verbatim
__global__ __launch_bounds__(256) void rsqrt_deg(const int* __restrict__ deg_i,
                                                 float* __restrict__ dis, int n)
{
    int i = blockIdx.x * 256 + threadIdx.x;
    if (i < n) dis[i] = rsqrtf((float)deg_i[i] + 1.0f);
}

// ---------------------------------------------------------------------------
// Shared phase-1 gather body (verbatim r10 gather_bn_relu numerics).
// Wave processes `node`; on q==0 writes the bf16-rounded row into hrow[r][*].
// ---------------------------------------------------------------------------
__device__ inline void gather_node_to_lds(const ushort16* __restrict__ h,
                                          const int* __restrict__ epad,
                                          const int* __restrict__ deg,
                                          const float* __restrict__ dis,
                                          const float* __restrict__ b,
                                          const float* __restrict__ gamma,
                                          const float* __restrict__ beta,
                                          const float* __restrict__ mean,
                                          const float* __restrict__ var,
                                          float (*hrow)[HDIM],
                                          int node, int r, int lane)
{
    const int q    = lane >> 4;
    const int ci   = (lane & 15) << 3;
    const int cnt_e = deg[node];
    const int base  = node * MAXDEG;
    const float dd  = dis[node];

    int   s_all  = 0;
    float nm_all = 0.f;
    if (lane < cnt_e) {
        s_all  = epad[base + lane];
        nm_all = dis[s_all] * dd;
    }

    float acc[8] = {0.f, 0.f, 0.f, 0.f, 0.f, 0.f, 0.f, 0.f};
    for (int j = q; j < cnt_e; j += 4) {
        int   s  = __shfl(s_all, j);
        float nm = __shfl(nm_all, j);
        uint4 v  = *(const uint4*)(h + (size_t)s * HDIM + ci);
        float2 f0 = bf2f(v.x), f1 = bf2f(v.y), f2 = bf2f(v.z), f3 = bf2f(v.w);
        acc[0] += f0.x * nm; acc[1] += f0.y * nm;
        acc[2] += f1.x * nm; acc[3] += f1.y * nm;
        acc[4] += f2.x * nm; acc[5] += f2.y * nm;
        acc[6] += f3.x * nm; acc[7] += f3.y * nm;
    }
    #pragma unroll
    for (int k = 0; k < 8; ++k) {
        acc[k] += __shfl_xor(acc[k], 16);
        acc[k] += __shfl_xor(acc[k], 32);
    }

    if (q == 0) {
        uint4 hv = *(const uint4*)(h + (size_t)node * HDIM + ci);
        float2 g0 = bf2f(hv.x), g1 = bf2f(hv.y), g2 = bf2f(hv.z), g3 = bf2f(hv.w);
        float a[8] = {acc[0] + g0.x * dd * dd, acc[1] + g0.y * dd * dd,
                      acc[2] + g1.x * dd * dd, acc[3] + g1.y * dd * dd,
                      acc[4] + g2.x * dd * dd, acc[5] + g2.y * dd * dd,
                      acc[6] + g3.x * dd * dd, acc[7] + g3.y * dd * dd};
        #pragma unroll
        for (int k = 0; k < 8; ++k) {
            int c = ci + k;
            float sc = gamma[c] * rsqrtf(var[c] + BN_EPS);
            float rr = (a[k] + b[c] - mean[c]) * sc + beta[c];
            // bf16 round-trip: downstream consumers see the exact values
            // r10's bufB held -> bit-path preserved.
            hrow[r][c] = bfround(fmaxf(rr, 0.f));
        }
    }
}

// ---------------------------------------------------------------------------
// Kernel A: gather1(+BN1+ReLU) for 32 nodes -> LDS, then verbatim gemm2
// (fp32 VALU, W2 staged per k0 chunk) -> Y (bf16). One dispatch, no bufB
// round-trip for the layer-1 -> layer-2 handoff.
// ---------------------------------------------------------------------------
__global__ __launch_bounds__(256) void gather1_gemm2(const ushort16* __restrict__ h,
                                                     const int* __restrict__ epad,
                                                     const int* __restrict__ deg,
                                                     const float* __restrict__ dis,
                                                     const float* __restrict__ b,
                                                     const float* __restrict__ gamma,
                                                     const float* __restrict__ beta,
                                                     const float* __restrict__ mean,
                                                     const float* __restrict__ var,
                                                     const float* __restrict__ W2,
                                                     ushort16* __restrict__ Y, int n)
{
    __shared__ float hrow[32][HDIM];
    __shared__ float ws[32][128];
    const int tid  = threadIdx.x;
    const int wave = tid >> 6, lane = tid & 63;
    const int node0 = blockIdx.x * 32;

    // ---- phase 1: gather 8 nodes per wave ----
    #pragma unroll 1
    for (int it = 0; it < 8; ++it) {
        int r = wave * 8 + it;
        int node = node0 + r;
        if (node < n)
            gather_node_to_lds(h, epad, deg, dis, b, gamma, beta, mean, var,
                               hrow, node, r, lane);
    }
    __syncthreads();

    // ---- phase 2: verbatim gemm2 inner, X-tile = hrow ----
    const int tx = tid & 31;
    const int ty = tid >> 5;

    float acc[4][4];
    #pragma unroll
    for (int i = 0; i < 4; ++i)
        #pragma unroll
        for (int j = 0; j < 4; ++j) acc[i][j] = 0.f;

    const int wr = tid >> 5;
    const int wc = (tid & 31) << 2;

    for (int k0 = 0; k0 < 128; k0 += 32) {
        #pragma unroll
        for (int i = 0; i < 4; ++i) {
            int kk = wr + i * 8;
            *(float4*)&ws[kk][wc] = *(const float4*)(W2 + (size_t)(k0 + kk) * HDIM + wc);
        }
        __syncthreads();
        #pragma unroll
        for (int kk = 0; kk < 32; kk += 4) {
            float4 wv[4];
            #pragma unroll
            for (int j = 0; j < 4; ++j) wv[j] = *(const float4*)&ws[kk + j][tx << 2];
            #pragma unroll
            for (int i = 0; i < 4; ++i) {
                float4 xr = *(const float4*)&hrow[ty * 4 + i][k0 + kk];
                acc[i][0] += xr.x * wv[0].x; acc[i][1] += xr.x * wv[0].y;
                acc[i][2] += xr.x * wv[0].z; acc[i][3] += xr.x * wv[0].w;
                acc[i][0] += xr.y * wv[1].x; acc[i][1] += xr.y * wv[1].y;
                acc[i][2] += xr.y * wv[1].z; acc[i][3] += xr.y * wv[1].w;
                acc[i][0] += xr.z * wv[2].x; acc[i][1] += xr.z * wv[2].y;
                acc[i][2] += xr.z * wv[2].z; acc[i][3] += xr.z * wv[2].w;
                acc[i][0] += xr.w * wv[3].x; acc[i][1] += xr.w * wv[3].y;
                acc[i][2] += xr.w * wv[3].z; acc[i][3] += xr.w * wv[3].w;
            }
        }
        __syncthreads();
    }
    #pragma unroll
    for (int i = 0; i < 4; ++i) {
        int grow = node0 + ty * 4 + i;
        if (grow < n) {
            uint2 o;
            o.x = packbf2(acc[i][0], acc[i][1]);
            o.y = packbf2(acc[i][2], acc[i][3]);
            *(uint2*)(Y + (size_t)grow * HDIM + (tx << 2)) = o;
        }
    }
}

// ---------------------------------------------------------------------------
// Kernel B: gather2(+BN2+ReLU) for 32 nodes -> LDS, then verbatim segmented
// pool over the block's consecutive nodes (batch sorted). No bufB write.
// ---------------------------------------------------------------------------
__global__ __launch_bounds__(256) void gather2_pool(const ushort16* __restrict__ h,
                                                    const int* __restrict__ epad,
                                                    const int* __restrict__ deg,
                                                    const float* __restrict__ dis,
                                                    const float* __restrict__ b,
                                                    const float* __restrict__ gamma,
                                                    const float* __restrict__ beta,
                                                    const float* __restrict__ mean,
                                                    const float* __restrict__ var,
                                                    const int* __restrict__ batch,
                                                    float* __restrict__ sums,
                                                    float* __restrict__ cnt, int n)
{
    __shared__ float hrow[32][HDIM];
    const int tid  = threadIdx.x;
    const int wave = tid >> 6, lane = tid & 63;
    const int node0 = blockIdx.x * 32;

    #pragma unroll 1
    for (int it = 0; it < 8; ++it) {
        int r = wave * 8 + it;
        int node = node0 + r;
        if (node < n)
            gather_node_to_lds(h, epad, deg, dis, b, gamma, beta, mean, var,
                               hrow, node, r, lane);
    }
    __syncthreads();

    // ---- phase 2: verbatim pool_sum body over hrow ----
    if (tid < 128) {
        int c = tid;
        int nvalid = min(node0 + 32, n) - node0;
        int curg = batch[node0];
        float acc = 0.f;
        int run = 0;
        for (int i = 0; i < nvalid; ++i) {
            int g   = batch[node0 + i];
            float v = hrow[i][c];
            if (g != curg) {
                atomicAdd(&sums[(size_t)curg * HDIM + c], acc);
                if (c == 0) atomicAdd(&cnt[curg], (float)run);
                acc = 0.f; run = 0; curg = g;
            }
            acc += v; run++;
        }
        atomicAdd(&sums[(size_t)curg * HDIM + c], acc);
        if (c == 0) atomicAdd(&cnt[curg], (float)run);
    }
}

// ---------------------------------------------------------------------------
// out[g][c] = (sums[g]/max(cnt[g],1)) . Wlin[:,c] + blin[c]  (verbatim)
// ---------------------------------------------------------------------------
__global__ __launch_bounds__(128) void final_lin(const float* __restrict__ sums,
                                                 const float* __restrict__ cnt,
                                                 const float* __restrict__ Wlin,
                                                 const float* __restrict__ blin,
                                                 float* __restrict__ out)
{
    __shared__ float red[NCLS][2];
    int g = blockIdx.x;
    int t = threadIdx.x;
    float ic = 1.f / fmaxf(cnt[g], 1.f);
    float v  = sums[(size_t)g * HDIM + t] * ic;
    float p[NCLS];
    #pragma unroll
    for (int c = 0; c < NCLS; ++c) p[c] = v * Wlin[t * NCLS + c];
    #pragma unroll
    for (int c = 0; c < NCLS; ++c) {
        float x = p[c];
        for (int off = 32; off > 0; off >>= 1) x += __shfl_down(x, off);
        if ((t & 63) == 0) red[c][t >> 6] = x;
    }
    __syncthreads();
    if (t < NCLS) out[g * NCLS + t] = red[t][0] + red[t][1] + blin[t];
}

// ---------------------------------------------------------------------------
extern "C" void kernel_launch(void* const* d_in, const int* in_sizes, int n_in,
                              void* d_out, int out_size, void* d_ws, size_t ws_size,
                              hipStream_t stream)
{
    const float* x     = (const float*)d_in[0];
    const int*   ei    = (const int*)d_in[1];
    const int*   srcp  = ei;
    const int*   dstp  = ei + N_EDGES;
    const int*   batch = (const int*)d_in[2];
    const float* W1    = (const float*)d_in[3];
    const float* b1    = (const float*)d_in[4];
    const float* g1    = (const float*)d_in[5];
    const float* be1   = (const float*)d_in[6];
    const float* m1    = (const float*)d_in[7];
    const float* v1    = (const float*)d_in[8];
    const float* W2    = (const float*)d_in[9];
    const float* b2    = (const float*)d_in[10];
    const float* g2    = (const float*)d_in[11];
    const float* be2   = (const float*)d_in[12];
    const float* m2    = (const float*)d_in[13];
    const float* v2    = (const float*)d_in[14];
    const float* Wlin  = (const float*)d_in[15];
    const float* blin  = (const float*)d_in[16];
    float*       out   = (float*)d_out;

    // workspace layout (verbatim r10, ~39 MiB):
    // bufA(bf16) | bufB(bf16) | epad(int) | deg | cnt | sums | dis
    ushort16* bufA = (ushort16*)d_ws;
    ushort16* bufB = bufA + (size_t)N_NODES * HDIM;
    int*   epad = (int*)(bufB + (size_t)N_NODES * HDIM);
    int*   deg  = epad + (size_t)N_NODES * MAXDEG;
    float* cnt  = (float*)(deg + N_NODES);
    float* sums = cnt + NGRAPH;
    float* dis  = sums + (size_t)NGRAPH * HDIM;

    // zero deg | cnt | sums in one contiguous memset
    hipMemsetAsync(deg, 0,
                   (N_NODES + NGRAPH + (size_t)NGRAPH * HDIM) * sizeof(float), stream);

    // ---- fused front: bucket (atomic-bound) + gemm1 fp32 (VALU-bound) ----
    front<<<FRONT_GRID, 256, 0, stream>>>(x, W1, bufA, srcp, dstp, deg, epad);
    rsqrt_deg<<<(N_NODES + 255) / 256, 256, 0, stream>>>(deg, dis, N_NODES);

    // ---- layer 1 aggregation + layer 2 GEMM (fused) ----
    gather1_gemm2<<<AB_BLOCKS, 256, 0, stream>>>(bufA, epad, deg, dis,
                                                 b1, g1, be1, m1, v1, W2, bufB, N_NODES);
    // ---- layer 2 aggregation + pool (fused) ----
    gather2_pool<<<AB_BLOCKS, 256, 0, stream>>>(bufB, epad, deg, dis,
                                                b2, g2, be2, m2, v2, batch,
                                                sums, cnt, N_NODES);
    // ---- head ----
    final_lin<<<NGRAPH, 128, 0, stream>>>(sums, cnt, Wlin, blin, out);
}

// Round 12
// 279.543 us; speedup vs baseline: 1.0133x; 1.0133x over previous
//
#include <hip/hip_runtime.h>
#include <hip/hip_bf16.h>

#define N_NODES 50000
#define N_EDGES 800000
#define HDIM 128
#define NGRAPH 512
#define NCLS 10
#define BN_EPS 1e-5f
#define MAXDEG 64   // in-deg ~ Poisson(16) over 50k bins; P(any>=64) ~ 1e-14

typedef unsigned int  uint32;
typedef unsigned short ushort16;

// bf16x2 (packed in a uint) -> float2
__device__ inline float2 bf2f(uint32 u) {
    return make_float2(__uint_as_float(u << 16), __uint_as_float(u & 0xffff0000u));
}
// fp32 -> bf16 bits, round-to-nearest-even
__device__ inline ushort16 f2bf(float f) {
    uint32 u = __float_as_uint(f);
    u += 0x7fffu + ((u >> 16) & 1u);
    return (ushort16)(u >> 16);
}
__device__ inline uint32 packbf2(float lo, float hi) {
    return (uint32)f2bf(lo) | ((uint32)f2bf(hi) << 16);
}

// NOTE (r6-r11): r10's numeric path = 4*2^-12 absmax (safe); any arithmetic
// re-association (e.g. dd2=dd*dd) lands at 11*2^-12 and fails post-timing.
// All accumulation orders below are VERBATIM r10. hrow holds bf16 bits ==
// exactly what r10's bufB held, so downstream consumers see identical bits.
// The 1-ahead preload only moves LOADS earlier; adds stay in r10 order.

#define GEMM1_BLOCKS 1563                  // ceil(50000/32)
#define FRONT_GRID (3 * GEMM1_BLOCKS)      // rem0: gemm1, rem1/2: bucket
#define AB_BLOCKS 1563                     // 32 nodes per block

// ---------------------------------------------------------------------------
// Fused front: rem!=0 blocks run bucket_edges (atomic-bound, VALU-idle),
// rem==0 blocks run gemm1 fp32 (VALU-bound). Bodies verbatim r10.
// ---------------------------------------------------------------------------
__global__ __launch_bounds__(256) void front(const float* __restrict__ x,
                                             const float* __restrict__ W1,
                                             ushort16* __restrict__ bufA,
                                             const int* __restrict__ src,
                                             const int* __restrict__ dst,
                                             int* __restrict__ deg,
                                             int* __restrict__ epad)
{
    __shared__ float xs[32][36];
    __shared__ float ws[32][128];
    const int tid = threadIdx.x;
    const int grp = blockIdx.x / 3, rem = blockIdx.x % 3;

    if (rem != 0) {
        int e = (grp * 2 + (rem - 1)) * 256 + tid;
        if (e < N_EDGES) {
            int d   = dst[e];
            int pos = atomicAdd(&deg[d], 1);
            epad[(size_t)d * MAXDEG + pos] = src[e];
        }
        return;
    }

    const int row0 = grp * 32;
    const int tx   = tid & 31;
    const int ty   = tid >> 5;

    float acc[4][4];
    #pragma unroll
    for (int i = 0; i < 4; ++i)
        #pragma unroll
        for (int j = 0; j < 4; ++j) acc[i][j] = 0.f;

    const int lr = tid >> 3;
    const int lk = (tid & 7) << 2;
    const int wr = tid >> 5;
    const int wc = (tid & 31) << 2;

    for (int k0 = 0; k0 < 128; k0 += 32) {
        float4 xv = make_float4(0.f, 0.f, 0.f, 0.f);
        int grow = row0 + lr;
        if (grow < N_NODES) xv = *(const float4*)(x + (size_t)grow * HDIM + k0 + lk);
        xs[lr][lk] = xv.x; xs[lr][lk + 1] = xv.y; xs[lr][lk + 2] = xv.z; xs[lr][lk + 3] = xv.w;
        #pragma unroll
        for (int i = 0; i < 4; ++i) {
            int kk = wr + i * 8;
            *(float4*)&ws[kk][wc] = *(const float4*)(W1 + (size_t)(k0 + kk) * HDIM + wc);
        }
        __syncthreads();
        #pragma unroll
        for (int kk = 0; kk < 32; kk += 4) {
            float4 wv[4];
            #pragma unroll
            for (int j = 0; j < 4; ++j) wv[j] = *(const float4*)&ws[kk + j][tx << 2];
            #pragma unroll
            for (int i = 0; i < 4; ++i) {
                float4 xr = *(const float4*)&xs[ty * 4 + i][kk];
                acc[i][0] += xr.x * wv[0].x; acc[i][1] += xr.x * wv[0].y;
                acc[i][2] += xr.x * wv[0].z; acc[i][3] += xr.x * wv[0].w;
                acc[i][0] += xr.y * wv[1].x; acc[i][1] += xr.y * wv[1].y;
                acc[i][2] += xr.y * wv[1].z; acc[i][3] += xr.y * wv[1].w;
                acc[i][0] += xr.z * wv[2].x; acc[i][1] += xr.z * wv[2].y;
                acc[i][2] += xr.z * wv[2].z; acc[i][3] += xr.z * wv[2].w;
                acc[i][0] += xr.w * wv[3].x; acc[i][1] += xr.w * wv[3].y;
                acc[i][2] += xr.w * wv[3].z; acc[i][3] += xr.w * wv[3].w;
            }
        }
        __syncthreads();
    }
    #pragma unroll
    for (int i = 0; i < 4; ++i) {
        int grow = row0 + ty * 4 + i;
        if (grow < N_NODES) {
            uint2 o;
            o.x = packbf2(acc[i][0], acc[i][1]);
            o.y = packbf2(acc[i][2], acc[i][3]);
            *(uint2*)(bufA + (size_t)grow * HDIM + (tx << 2)) = o;
        }
    }
}

// dis[i] = rsqrt(deg[i]+1); also zeroes cnt|sums (runs well before pool use)
#define CZ_DWORDS (NGRAPH + NGRAPH * HDIM)
__global__ __launch_bounds__(256) void rsqrt_deg(const int* __restrict__ deg_i,
                                                 float* __restrict__ dis,
                                                 uint32* __restrict__ cz, int n)
{
    int i = blockIdx.x * 256 + threadIdx.x;
    if (i < n) dis[i] = rsqrtf((float)deg_i[i] + 1.0f);
    if (i < CZ_DWORDS) cz[i] = 0;
}

// ---------------------------------------------------------------------------
// Shared phase-1 gather body — r10 numerics, 1-ahead load pipelining.
// Writes the bf16-rounded row bits into hrow[r][*] (== r10's bufB bits).
// ---------------------------------------------------------------------------
__device__ inline void gather_node_to_lds(const ushort16* __restrict__ h,
                                          const int* __restrict__ epad,
                                          const int* __restrict__ deg,
                                          const float* __restrict__ dis,
                                          const float* __restrict__ b,
                                          const float* __restrict__ gamma,
                                          const float* __restrict__ beta,
                                          const float* __restrict__ mean,
                                          const float* __restrict__ var,
                                          ushort16 (*hrow)[HDIM],
                                          int node, int r, int lane)
{
    const int q    = lane >> 4;
    const int ci   = (lane & 15) << 3;
    const int cnt_e = deg[node];
    const int base  = node * MAXDEG;
    const float dd  = dis[node];

    int   s_all  = 0;
    float nm_all = 0.f;
    if (lane < cnt_e) {
        s_all  = epad[base + lane];
        nm_all = dis[s_all] * dd;
    }

    float acc[8] = {0.f, 0.f, 0.f, 0.f, 0.f, 0.f, 0.f, 0.f};
    // 1-ahead pipeline; accumulation order identical to r10's j = q,q+4,...
    int j = q;
    int   s_cur  = __shfl(s_all, j);        // j < 4 always valid lane idx
    float nm_cur = __shfl(nm_all, j);
    uint4 v_cur  = make_uint4(0, 0, 0, 0);
    if (j < cnt_e)
        v_cur = *(const uint4*)(h + (size_t)s_cur * HDIM + ci);
    while (j < cnt_e) {
        const int jn = j + 4;
        int   s_nxt  = __shfl(s_all, jn & 63);    // wave-uniform shfl, no divergence
        float nm_nxt = __shfl(nm_all, jn & 63);
        uint4 v_nxt  = make_uint4(0, 0, 0, 0);
        if (jn < cnt_e)
            v_nxt = *(const uint4*)(h + (size_t)s_nxt * HDIM + ci);
        float2 f0 = bf2f(v_cur.x), f1 = bf2f(v_cur.y), f2 = bf2f(v_cur.z), f3 = bf2f(v_cur.w);
        acc[0] += f0.x * nm_cur; acc[1] += f0.y * nm_cur;
        acc[2] += f1.x * nm_cur; acc[3] += f1.y * nm_cur;
        acc[4] += f2.x * nm_cur; acc[5] += f2.y * nm_cur;
        acc[6] += f3.x * nm_cur; acc[7] += f3.y * nm_cur;
        v_cur = v_nxt; nm_cur = nm_nxt; j = jn;
    }
    #pragma unroll
    for (int k = 0; k < 8; ++k) {
        acc[k] += __shfl_xor(acc[k], 16);
        acc[k] += __shfl_xor(acc[k], 32);
    }

    if (q == 0) {
        uint4 hv = *(const uint4*)(h + (size_t)node * HDIM + ci);
        float2 g0 = bf2f(hv.x), g1 = bf2f(hv.y), g2 = bf2f(hv.z), g3 = bf2f(hv.w);
        // keep r10's exact association: g*dd*dd, NOT g*(dd*dd)
        float a[8] = {acc[0] + g0.x * dd * dd, acc[1] + g0.y * dd * dd,
                      acc[2] + g1.x * dd * dd, acc[3] + g1.y * dd * dd,
                      acc[4] + g2.x * dd * dd, acc[5] + g2.y * dd * dd,
                      acc[6] + g3.x * dd * dd, acc[7] + g3.y * dd * dd};
        #pragma unroll
        for (int k = 0; k < 8; ++k) {
            int c = ci + k;
            float sc = gamma[c] * rsqrtf(var[c] + BN_EPS);
            float rr = (a[k] + b[c] - mean[c]) * sc + beta[c];
            hrow[r][c] = f2bf(fmaxf(rr, 0.f));   // bf16 bits == r10's bufB
        }
    }
}

// ---------------------------------------------------------------------------
// Kernel A: gather1(+BN1+ReLU) for 32 nodes -> LDS (bf16), then verbatim
// gemm2 (fp32 VALU) reading hrow bits == r10's bufB. LDS 24 KB.
// ---------------------------------------------------------------------------
__global__ __launch_bounds__(256) void gather1_gemm2(const ushort16* __restrict__ h,
                                                     const int* __restrict__ epad,
                                                     const int* __restrict__ deg,
                                                     const float* __restrict__ dis,
                                                     const float* __restrict__ b,
                                                     const float* __restrict__ gamma,
                                                     const float* __restrict__ beta,
                                                     const float* __restrict__ mean,
                                                     const float* __restrict__ var,
                                                     const float* __restrict__ W2,
                                                     ushort16* __restrict__ Y, int n)
{
    __shared__ ushort16 hrow[32][HDIM];
    __shared__ float ws[32][128];
    const int tid  = threadIdx.x;
    const int wave = tid >> 6, lane = tid & 63;
    const int node0 = blockIdx.x * 32;

    #pragma unroll 1
    for (int it = 0; it < 8; ++it) {
        int r = wave * 8 + it;
        int node = node0 + r;
        if (node < n)
            gather_node_to_lds(h, epad, deg, dis, b, gamma, beta, mean, var,
                               hrow, node, r, lane);
        else if ((lane >> 4) == 0) {              // zero-fill tail rows
            int ci = (lane & 15) << 3;
            #pragma unroll
            for (int k = 0; k < 8; ++k) hrow[r][ci + k] = 0;
        }
    }
    __syncthreads();

    // ---- phase 2: verbatim gemm2 inner, X-tile = hrow (bf16 -> fp32) ----
    const int tx = tid & 31;
    const int ty = tid >> 5;

    float acc[4][4];
    #pragma unroll
    for (int i = 0; i < 4; ++i)
        #pragma unroll
        for (int j = 0; j < 4; ++j) acc[i][j] = 0.f;

    const int wr = tid >> 5;
    const int wc = (tid & 31) << 2;

    for (int k0 = 0; k0 < 128; k0 += 32) {
        #pragma unroll
        for (int i = 0; i < 4; ++i) {
            int kk = wr + i * 8;
            *(float4*)&ws[kk][wc] = *(const float4*)(W2 + (size_t)(k0 + kk) * HDIM + wc);
        }
        __syncthreads();
        #pragma unroll
        for (int kk = 0; kk < 32; kk += 4) {
            float4 wv[4];
            #pragma unroll
            for (int j = 0; j < 4; ++j) wv[j] = *(const float4*)&ws[kk + j][tx << 2];
            #pragma unroll
            for (int i = 0; i < 4; ++i) {
                uint2 u = *(const uint2*)&hrow[ty * 4 + i][k0 + kk];  // 4 bf16
                float2 xa = bf2f(u.x), xb = bf2f(u.y);
                float4 xr = make_float4(xa.x, xa.y, xb.x, xb.y);
                acc[i][0] += xr.x * wv[0].x; acc[i][1] += xr.x * wv[0].y;
                acc[i][2] += xr.x * wv[0].z; acc[i][3] += xr.x * wv[0].w;
                acc[i][0] += xr.y * wv[1].x; acc[i][1] += xr.y * wv[1].y;
                acc[i][2] += xr.y * wv[1].z; acc[i][3] += xr.y * wv[1].w;
                acc[i][0] += xr.z * wv[2].x; acc[i][1] += xr.z * wv[2].y;
                acc[i][2] += xr.z * wv[2].z; acc[i][3] += xr.z * wv[2].w;
                acc[i][0] += xr.w * wv[3].x; acc[i][1] += xr.w * wv[3].y;
                acc[i][2] += xr.w * wv[3].z; acc[i][3] += xr.w * wv[3].w;
            }
        }
        __syncthreads();
    }
    #pragma unroll
    for (int i = 0; i < 4; ++i) {
        int grow = node0 + ty * 4 + i;
        if (grow < n) {
            uint2 o;
            o.x = packbf2(acc[i][0], acc[i][1]);
            o.y = packbf2(acc[i][2], acc[i][3]);
            *(uint2*)(Y + (size_t)grow * HDIM + (tx << 2)) = o;
        }
    }
}

// ---------------------------------------------------------------------------
// Kernel B: gather2(+BN2+ReLU) for 32 nodes -> LDS (bf16), then verbatim
// segmented pool over the block's consecutive nodes (batch sorted). LDS 8 KB.
// ---------------------------------------------------------------------------
__global__ __launch_bounds__(256) void gather2_pool(const ushort16* __restrict__ h,
                                                    const int* __restrict__ epad,
                                                    const int* __restrict__ deg,
                                                    const float* __restrict__ dis,
                                                    const float* __restrict__ b,
                                                    const float* __restrict__ gamma,
                                                    const float* __restrict__ beta,
                                                    const float* __restrict__ mean,
                                                    const float* __restrict__ var,
                                                    const int* __restrict__ batch,
                                                    float* __restrict__ sums,
                                                    float* __restrict__ cnt, int n)
{
    __shared__ ushort16 hrow[32][HDIM];
    const int tid  = threadIdx.x;
    const int wave = tid >> 6, lane = tid & 63;
    const int node0 = blockIdx.x * 32;

    #pragma unroll 1
    for (int it = 0; it < 8; ++it) {
        int r = wave * 8 + it;
        int node = node0 + r;
        if (node < n)
            gather_node_to_lds(h, epad, deg, dis, b, gamma, beta, mean, var,
                               hrow, node, r, lane);
    }
    __syncthreads();

    if (tid < 128) {
        int c = tid;
        int nvalid = min(node0 + 32, n) - node0;
        int curg = batch[node0];
        float acc = 0.f;
        int run = 0;
        for (int i = 0; i < nvalid; ++i) {
            int g   = batch[node0 + i];
            float v = __uint_as_float((uint32)hrow[i][c] << 16);   // == r10 pool read
            if (g != curg) {
                atomicAdd(&sums[(size_t)curg * HDIM + c], acc);
                if (c == 0) atomicAdd(&cnt[curg], (float)run);
                acc = 0.f; run = 0; curg = g;
            }
            acc += v; run++;
        }
        atomicAdd(&sums[(size_t)curg * HDIM + c], acc);
        if (c == 0) atomicAdd(&cnt[curg], (float)run);
    }
}

// ---------------------------------------------------------------------------
// out[g][c] = (sums[g]/max(cnt[g],1)) . Wlin[:,c] + blin[c]  (verbatim)
// ---------------------------------------------------------------------------
__global__ __launch_bounds__(128) void final_lin(const float* __restrict__ sums,
                                                 const float* __restrict__ cnt,
                                                 const float* __restrict__ Wlin,
                                                 const float* __restrict__ blin,
                                                 float* __restrict__ out)
{
    __shared__ float red[NCLS][2];
    int g = blockIdx.x;
    int t = threadIdx.x;
    float ic = 1.f / fmaxf(cnt[g], 1.f);
    float v  = sums[(size_t)g * HDIM + t] * ic;
    float p[NCLS];
    #pragma unroll
    for (int c = 0; c < NCLS; ++c) p[c] = v * Wlin[t * NCLS + c];
    #pragma unroll
    for (int c = 0; c < NCLS; ++c) {
        float x = p[c];
        for (int off = 32; off > 0; off >>= 1) x += __shfl_down(x, off);
        if ((t & 63) == 0) red[c][t >> 6] = x;
    }
    __syncthreads();
    if (t < NCLS) out[g * NCLS + t] = red[t][0] + red[t][1] + blin[t];
}

// ---------------------------------------------------------------------------
extern "C" void kernel_launch(void* const* d_in, const int* in_sizes, int n_in,
                              void* d_out, int out_size, void* d_ws, size_t ws_size,
                              hipStream_t stream)
{
    const float* x     = (const float*)d_in[0];
    const int*   ei    = (const int*)d_in[1];
    const int*   srcp  = ei;
    const int*   dstp  = ei + N_EDGES;
    const int*   batch = (const int*)d_in[2];
    const float* W1    = (const float*)d_in[3];
    const float* b1    = (const float*)d_in[4];
    const float* g1    = (const float*)d_in[5];
    const float* be1   = (const float*)d_in[6];
    const float* m1    = (const float*)d_in[7];
    const float* v1    = (const float*)d_in[8];
    const float* W2    = (const float*)d_in[9];
    const float* b2    = (const float*)d_in[10];
    const float* g2    = (const float*)d_in[11];
    const float* be2   = (const float*)d_in[12];
    const float* m2    = (const float*)d_in[13];
    const float* v2    = (const float*)d_in[14];
    const float* Wlin  = (const float*)d_in[15];
    const float* blin  = (const float*)d_in[16];
    float*       out   = (float*)d_out;

    // workspace layout (verbatim r10, ~39 MiB):
    // bufA(bf16) | bufB(bf16) | epad(int) | deg | cnt | sums | dis
    ushort16* bufA = (ushort16*)d_ws;
    ushort16* bufB = bufA + (size_t)N_NODES * HDIM;
    int*   epad = (int*)(bufB + (size_t)N_NODES * HDIM);
    int*   deg  = epad + (size_t)N_NODES * MAXDEG;
    float* cnt  = (float*)(deg + N_NODES);
    float* sums = cnt + NGRAPH;
    float* dis  = sums + (size_t)NGRAPH * HDIM;

    // zero deg only (cnt|sums are zeroed inside rsqrt_deg)
    hipMemsetAsync(deg, 0, N_NODES * sizeof(int), stream);

    // ---- fused front: bucket (atomic-bound) + gemm1 fp32 (VALU-bound) ----
    front<<<FRONT_GRID, 256, 0, stream>>>(x, W1, bufA, srcp, dstp, deg, epad);
    rsqrt_deg<<<(CZ_DWORDS + 255) / 256, 256, 0, stream>>>(deg, dis, (uint32*)cnt, N_NODES);

    // ---- layer 1 aggregation + layer 2 GEMM (fused) ----
    gather1_gemm2<<<AB_BLOCKS, 256, 0, stream>>>(bufA, epad, deg, dis,
                                                 b1, g1, be1, m1, v1, W2, bufB, N_NODES);
    // ---- layer 2 aggregation + pool (fused) ----
    gather2_pool<<<AB_BLOCKS, 256, 0, stream>>>(bufB, epad, deg, dis,
                                                b2, g2, be2, m2, v2, batch,
                                                sums, cnt, N_NODES);
    // ---- head ----
    final_lin<<<NGRAPH, 128, 0, stream>>>(sums, cnt, Wlin, blin, out);
}